// Round 1
// baseline (978.426 us; speedup 1.0000x reference)
//
#include <hip/hip_runtime.h>
#include <math.h>

#define D_MODEL 1024
#define SEQ 2048
#define BATCH 8
#define ROWS (BATCH*SEQ)   // 16384

typedef __attribute__((ext_vector_type(8))) short bf16x8;  // 8 bf16 (4 VGPRs)
typedef __attribute__((ext_vector_type(4))) float f32x4;

__device__ __forceinline__ unsigned short f2bf(float f) {
  union { float f; unsigned u; } x; x.f = f;
  unsigned r = x.u + 0x7fffu + ((x.u >> 16) & 1u);   // RNE
  return (unsigned short)(r >> 16);
}

// LDS row stride: 36 shorts = 9 dwords (odd) -> conflict-light for b64 frag
// reads (16 lanes hit 16 distinct banks) and ~4-way worst on NN u16 scatter.
#define LDK 36

// ASRC/BSRC: 0=fp32 source, 1=bf16(ushort) source
// BL: 0 = B is [N x K] row-major (NT), 1 = B is [K x N] row-major (NN)
// EPI: 0 = store bf16 C; 1 = exp epilogue (P + l/t row sums); 2 = /l + bias, fp32 store
template<int ASRC, int BSRC, int BL, int EPI>
__global__ __launch_bounds__(256, 2)
void gemm_k(const void* __restrict__ Ap, const void* __restrict__ Bp,
            void* __restrict__ Cp, int lda, int ldb, int ldc, int K,
            size_t sA, size_t sB, size_t sC, float scale,
            float* __restrict__ lsum, float* __restrict__ tsum, int lstride,
            const float* __restrict__ bias)
{
  __shared__ unsigned short As[128 * LDK];
  __shared__ unsigned short Bs[128 * LDK];
  const int tid  = threadIdx.x;
  const int lane = tid & 63, wid = tid >> 6;
  const int quad = lane >> 4, l16 = lane & 15;
  const int wm = (wid >> 1) * 64, wn = (wid & 1) * 64;
  const int m0 = blockIdx.y * 128, n0 = blockIdx.x * 128;
  const int bz = blockIdx.z;

  f32x4 acc[4][4];
#pragma unroll
  for (int i = 0; i < 4; i++)
#pragma unroll
    for (int j = 0; j < 4; j++) acc[i][j] = (f32x4){0.f, 0.f, 0.f, 0.f};

  for (int kt = 0; kt < K; kt += 32) {
    // ---------------- stage A tile (128 rows x 32 k) ----------------
    if constexpr (ASRC == 0) {
      const float* A = (const float*)Ap + (size_t)bz * sA;
#pragma unroll
      for (int p = 0; p < 4; p++) {
        int row = p * 32 + (tid >> 3);
        int cs  = (tid & 7) * 4;
        float4 v = *(const float4*)(A + (size_t)(m0 + row) * lda + kt + cs);
        ushort4 w;
        w.x = f2bf(v.x); w.y = f2bf(v.y); w.z = f2bf(v.z); w.w = f2bf(v.w);
        *(ushort4*)&As[row * LDK + cs] = w;
      }
    } else {
      const unsigned short* A = (const unsigned short*)Ap + (size_t)bz * sA;
#pragma unroll
      for (int p = 0; p < 2; p++) {
        int row = p * 64 + (tid >> 2);
        int cs  = (tid & 3) * 8;
        uint4 v = *(const uint4*)(A + (size_t)(m0 + row) * lda + kt + cs);
        *(uint2*)&As[row * LDK + cs]     = make_uint2(v.x, v.y);
        *(uint2*)&As[row * LDK + cs + 4] = make_uint2(v.z, v.w);
      }
    }
    // ---------------- stage B tile into Bs[n][k] ----------------
    if constexpr (BL == 0) {           // B is [N x K]
      if constexpr (BSRC == 0) {
        const float* B = (const float*)Bp + (size_t)bz * sB;
#pragma unroll
        for (int p = 0; p < 4; p++) {
          int row = p * 32 + (tid >> 3);
          int cs  = (tid & 7) * 4;
          float4 v = *(const float4*)(B + (size_t)(n0 + row) * ldb + kt + cs);
          ushort4 w;
          w.x = f2bf(v.x); w.y = f2bf(v.y); w.z = f2bf(v.z); w.w = f2bf(v.w);
          *(ushort4*)&Bs[row * LDK + cs] = w;
        }
      } else {
        const unsigned short* B = (const unsigned short*)Bp + (size_t)bz * sB;
#pragma unroll
        for (int p = 0; p < 2; p++) {
          int row = p * 64 + (tid >> 2);
          int cs  = (tid & 3) * 8;
          uint4 v = *(const uint4*)(B + (size_t)(n0 + row) * ldb + kt + cs);
          *(uint2*)&Bs[row * LDK + cs]     = make_uint2(v.x, v.y);
          *(uint2*)&Bs[row * LDK + cs + 4] = make_uint2(v.z, v.w);
        }
      }
    } else {                           // B is [K x N] -> transpose in staging
      if constexpr (BSRC == 0) {
        const float* B = (const float*)Bp + (size_t)bz * sB;
#pragma unroll
        for (int p = 0; p < 4; p++) {
          int kr = p * 8 + (tid >> 5);
          int cs = (tid & 31) * 4;
          float4 v = *(const float4*)(B + (size_t)(kt + kr) * ldb + n0 + cs);
          Bs[(cs + 0) * LDK + kr] = f2bf(v.x);
          Bs[(cs + 1) * LDK + kr] = f2bf(v.y);
          Bs[(cs + 2) * LDK + kr] = f2bf(v.z);
          Bs[(cs + 3) * LDK + kr] = f2bf(v.w);
        }
      } else {
        const unsigned short* B = (const unsigned short*)Bp + (size_t)bz * sB;
#pragma unroll
        for (int p = 0; p < 2; p++) {
          int kr = p * 16 + (tid >> 4);
          int cs = (tid & 15) * 8;
          unsigned short vv[8];
          *(uint4*)vv = *(const uint4*)(B + (size_t)(kt + kr) * ldb + n0 + cs);
#pragma unroll
          for (int i = 0; i < 8; i++) Bs[(cs + i) * LDK + kr] = vv[i];
        }
      }
    }
    __syncthreads();

    bf16x8 af[4], bf[4];
#pragma unroll
    for (int mi = 0; mi < 4; mi++) {
      const unsigned short* s = &As[(wm + mi * 16 + l16) * LDK + quad * 8];
      union { bf16x8 v; uint2 u[2]; } x;
      x.u[0] = *(const uint2*)s; x.u[1] = *(const uint2*)(s + 4);
      af[mi] = x.v;
    }
#pragma unroll
    for (int ni = 0; ni < 4; ni++) {
      const unsigned short* s = &Bs[(wn + ni * 16 + l16) * LDK + quad * 8];
      union { bf16x8 v; uint2 u[2]; } x;
      x.u[0] = *(const uint2*)s; x.u[1] = *(const uint2*)(s + 4);
      bf[ni] = x.v;
    }
#pragma unroll
    for (int mi = 0; mi < 4; mi++)
#pragma unroll
      for (int ni = 0; ni < 4; ni++)
        acc[mi][ni] = __builtin_amdgcn_mfma_f32_16x16x32_bf16(
            af[mi], bf[ni], acc[mi][ni], 0, 0, 0);
    __syncthreads();
  }

  // ---------------- epilogue ----------------
  // C/D layout: col = lane&15, row = quad*4 + reg  [m89-verified]
  if constexpr (EPI == 0) {
    unsigned short* C = (unsigned short*)Cp + (size_t)bz * sC;
#pragma unroll
    for (int mi = 0; mi < 4; mi++)
#pragma unroll
      for (int r = 0; r < 4; r++) {
        int grow = m0 + wm + mi * 16 + quad * 4 + r;
#pragma unroll
        for (int ni = 0; ni < 4; ni++) {
          int gcol = n0 + wn + ni * 16 + l16;
          C[(size_t)grow * ldc + gcol] = f2bf(acc[mi][ni][r]);
        }
      }
  } else if constexpr (EPI == 1) {
    unsigned short* C = (unsigned short*)Cp + (size_t)bz * sC;
#pragma unroll
    for (int mi = 0; mi < 4; mi++)
#pragma unroll
      for (int r = 0; r < 4; r++) {
        int grow = m0 + wm + mi * 16 + quad * 4 + r;
        float es = 0.f, ts = 0.f;
#pragma unroll
        for (int ni = 0; ni < 4; ni++) {
          int gcol = n0 + wn + ni * 16 + l16;
          float s = acc[mi][ni][r] * scale;
          float e = __expf(s);
          es += e; ts += s * e;
          C[(size_t)grow * ldc + gcol] = f2bf(e);
        }
#pragma unroll
        for (int off = 1; off < 16; off <<= 1) {
          es += __shfl_xor(es, off, 64);
          ts += __shfl_xor(ts, off, 64);
        }
        if (l16 == 0) {
          atomicAdd(&lsum[bz * lstride + grow], es);
          atomicAdd(&tsum[bz * lstride + grow], ts);
        }
      }
  } else {
    float* C = (float*)Cp + (size_t)bz * sC;
#pragma unroll
    for (int mi = 0; mi < 4; mi++)
#pragma unroll
      for (int r = 0; r < 4; r++) {
        int grow = m0 + wm + mi * 16 + quad * 4 + r;
        float linv = 1.0f / lsum[bz * lstride + grow];
#pragma unroll
        for (int ni = 0; ni < 4; ni++) {
          int gcol = n0 + wn + ni * 16 + l16;
          C[(size_t)grow * ldc + gcol] = acc[mi][ni][r] * linv + bias[gcol];
        }
      }
  }
}

// In-place layernorm over rows of 1024 floats.
__global__ __launch_bounds__(256)
void ln_k(float* __restrict__ out, const float* __restrict__ gamma,
          const float* __restrict__ beta)
{
  const size_t row = blockIdx.x;
  float* p = out + row * D_MODEL;
  const int tid = threadIdx.x;
  float v[4]; float s = 0.f, sq = 0.f;
#pragma unroll
  for (int i = 0; i < 4; i++) {
    v[i] = p[tid + i * 256]; s += v[i]; sq += v[i] * v[i];
  }
#pragma unroll
  for (int off = 1; off < 64; off <<= 1) {
    s += __shfl_xor(s, off, 64);
    sq += __shfl_xor(sq, off, 64);
  }
  __shared__ float sh[8];
  int wv = tid >> 6, lane = tid & 63;
  if (lane == 0) { sh[wv] = s; sh[4 + wv] = sq; }
  __syncthreads();
  s  = sh[0] + sh[1] + sh[2] + sh[3];
  sq = sh[4] + sh[5] + sh[6] + sh[7];
  float mean = s * (1.f / 1024.f);
  float var  = sq * (1.f / 1024.f) - mean * mean;
  float rstd = rsqrtf(var + 1e-5f);
#pragma unroll
  for (int i = 0; i < 4; i++) {
    int c = tid + i * 256;
    p[c] = (v[i] - mean) * rstd * gamma[c] + beta[c];
  }
}

// syntony = clip(1 - mean(log l - t/l)/log(S), 0, 1)
__global__ __launch_bounds__(256)
void syn_k(const float* __restrict__ l, const float* __restrict__ t,
           float* __restrict__ out)
{
  float s = 0.f;
  for (int r = threadIdx.x; r < ROWS; r += 256) {
    float lv = l[r];
    s += logf(lv) - t[r] / lv;
  }
#pragma unroll
  for (int off = 1; off < 64; off <<= 1) s += __shfl_xor(s, off, 64);
  __shared__ float sh[4];
  if ((threadIdx.x & 63) == 0) sh[threadIdx.x >> 6] = s;
  __syncthreads();
  if (threadIdx.x == 0) {
    float tot  = sh[0] + sh[1] + sh[2] + sh[3];
    float ment = tot / (float)ROWS;
    float syn  = 1.0f - ment / logf((float)SEQ);
    syn = fminf(fmaxf(syn, 0.f), 1.f);
    out[(size_t)ROWS * D_MODEL] = syn;
  }
}

extern "C" void kernel_launch(void* const* d_in, const int* in_sizes, int n_in,
                              void* d_out, int out_size, void* d_ws, size_t ws_size,
                              hipStream_t stream)
{
  const float* q     = (const float*)d_in[0];
  const float* k     = (const float*)d_in[1];
  const float* v     = (const float*)d_in[2];
  const float* hw    = (const float*)d_in[3];
  const float* hb    = (const float*)d_in[4];
  const float* gamma = (const float*)d_in[5];
  const float* beta  = (const float*)d_in[6];
  float* out = (float*)d_out;

  char* ws = (char*)d_ws;
  unsigned short* P  = (unsigned short*)ws;                         // 8*2048*2048 bf16 = 64MB
  unsigned short* VW = (unsigned short*)(ws + (size_t)BATCH * SEQ * SEQ * 2); // 16384*1024 bf16 = 32MB
  float* lsum = (float*)(ws + (size_t)BATCH * SEQ * SEQ * 2 + (size_t)ROWS * D_MODEL * 2);
  float* tsum = lsum + ROWS;

  hipMemsetAsync(lsum, 0, 2 * ROWS * sizeof(float), stream);

  // K0: VW = V @ W  (flat M=16384, N=1024, K=1024), fp32 A, fp32 B [KxN] -> bf16
  gemm_k<0, 0, 1, 0><<<dim3(D_MODEL / 128, ROWS / 128, 1), 256, 0, stream>>>(
      v, hw, VW, D_MODEL, D_MODEL, D_MODEL, D_MODEL,
      0, 0, 0, 1.f, nullptr, nullptr, 0, nullptr);

  // K1: P = exp(Q K^T / 32) per batch (M=2048, N=2048, K=1024), B = K rows [NxK]
  gemm_k<0, 0, 0, 1><<<dim3(SEQ / 128, SEQ / 128, BATCH), 256, 0, stream>>>(
      q, k, P, D_MODEL, D_MODEL, SEQ, D_MODEL,
      (size_t)SEQ * D_MODEL, (size_t)SEQ * D_MODEL, (size_t)SEQ * SEQ,
      0.03125f, lsum, tsum, SEQ, nullptr);

  // K2: H = (P @ VW) / l + bias  per batch (M=2048, N=1024, K=2048), bf16 A, bf16 B [KxN]
  gemm_k<1, 1, 1, 2><<<dim3(D_MODEL / 128, SEQ / 128, BATCH), 256, 0, stream>>>(
      P, VW, out, SEQ, D_MODEL, D_MODEL, SEQ,
      (size_t)SEQ * SEQ, (size_t)SEQ * D_MODEL, (size_t)SEQ * D_MODEL,
      1.f, lsum, tsum, SEQ, hb);

  ln_k<<<ROWS, 256, 0, stream>>>(out, gamma, beta);
  syn_k<<<1, 256, 0, stream>>>(lsum, tsum, out);
}

// Round 3
// 512.123 us; speedup vs baseline: 1.9105x; 1.9105x over previous
//
#include <hip/hip_runtime.h>
#include <math.h>

#define D_MODEL 1024
#define SEQ 2048
#define BATCH 8
#define ROWS (BATCH*SEQ)   // 16384

typedef __attribute__((ext_vector_type(8))) short bf16x8;  // 8 bf16 (4 VGPRs)
typedef __attribute__((ext_vector_type(4))) float f32x4;

__device__ __forceinline__ unsigned short f2bf(float f) {
  union { float f; unsigned u; } x; x.f = f;
  unsigned r = x.u + 0x7fffu + ((x.u >> 16) & 1u);   // RNE
  return (unsigned short)(r >> 16);
}

// async 16B global -> LDS (direct-to-shared DMA; LDS dest is wave-uniform
// base + lane*16, which our tid*16B layout satisfies exactly)
__device__ __forceinline__ void gld16(const unsigned short* g, unsigned short* l) {
  __builtin_amdgcn_global_load_lds(
      (const __attribute__((address_space(1))) unsigned int*)g,
      (__attribute__((address_space(3))) unsigned int*)l, 16, 0, 0);
}

// ---------------------------------------------------------------------------
// m97-style NT bf16 GEMM: C[128x128] per block, BK=32, 4 waves x (4x4 16x16x32).
// LDS packed stride 32 shorts (global_load_lds needs contiguous lane order).
// k-chunk XOR swizzle: LDS slot s of row R holds global 16B-chunk (s-(R>>1))&3,
// so quarter-wave ds_read_b128 frag reads hit all 32 banks exactly 2x (free).
// EPI: 0 = bf16 store; 1 = exp + l/t row-sum atomics; 2 = *1/l + bias, fp32.
// ---------------------------------------------------------------------------
template<int EPI>
__global__ __launch_bounds__(256, 2)
void gemm_a(const unsigned short* __restrict__ A, const unsigned short* __restrict__ B,
            void* __restrict__ Cp, int lda, int ldb, int ldc, int K,
            size_t sA, size_t sB, size_t sC, float scale,
            float* __restrict__ lsum, float* __restrict__ tsum, int lstride,
            const float* __restrict__ bias)
{
  __shared__ unsigned short As[128 * 32];
  __shared__ unsigned short Bs[128 * 32];
  const int tid  = threadIdx.x;
  const int lane = tid & 63, wid = tid >> 6;
  const int quad = lane >> 4, l16 = lane & 15;
  const int wm = (wid >> 1) * 64, wn = (wid & 1) * 64;
  const int m0 = blockIdx.y * 128, n0 = blockIdx.x * 128;
  const int bz = blockIdx.z;

  // staging coords: thread stages rows r0 and r0+64; the global 16B k-chunk is
  // the swizzle-inverse of its LDS slot so readers find chunk q at slot
  // s=(q+(R>>1))&3.
  const int r0 = tid >> 2;                         // 0..63
  const int s0 = tid & 3;                          // LDS 16B-slot
  const int u0 = (s0 - (r0 >> 1)) & 3;             // global chunk, row r0
  const int u1 = (s0 - ((r0 + 64) >> 1)) & 3;      // global chunk, row r0+64

  const unsigned short* Ag0 = A + (size_t)bz * sA + (size_t)(m0 + r0)      * lda + u0 * 8;
  const unsigned short* Ag1 = A + (size_t)bz * sA + (size_t)(m0 + r0 + 64) * lda + u1 * 8;
  const unsigned short* Bg0 = B + (size_t)bz * sB + (size_t)(n0 + r0)      * ldb + u0 * 8;
  const unsigned short* Bg1 = B + (size_t)bz * sB + (size_t)(n0 + r0 + 64) * ldb + u1 * 8;
  unsigned short* Al0 = &As[r0 * 32 + s0 * 8];
  unsigned short* Al1 = Al0 + 64 * 32;
  unsigned short* Bl0 = &Bs[r0 * 32 + s0 * 8];
  unsigned short* Bl1 = Bl0 + 64 * 32;

  f32x4 acc[4][4];
#pragma unroll
  for (int i = 0; i < 4; i++)
#pragma unroll
    for (int j = 0; j < 4; j++) acc[i][j] = (f32x4){0.f, 0.f, 0.f, 0.f};

  for (int kt = 0; kt < K; kt += 32) {
    gld16(Ag0 + kt, Al0);
    gld16(Ag1 + kt, Al1);
    gld16(Bg0 + kt, Bl0);
    gld16(Bg1 + kt, Bl1);
    __syncthreads();   // drains vmcnt -> LDS valid

    bf16x8 af[4], bfr[4];
#pragma unroll
    for (int mi = 0; mi < 4; mi++) {
      const int R = wm + mi * 16 + l16;
      const int s = (quad + (R >> 1)) & 3;
      union { bf16x8 v; uint4 u; } x;
      x.u = *(const uint4*)&As[R * 32 + s * 8];
      af[mi] = x.v;
    }
#pragma unroll
    for (int ni = 0; ni < 4; ni++) {
      const int R = wn + ni * 16 + l16;
      const int s = (quad + (R >> 1)) & 3;
      union { bf16x8 v; uint4 u; } x;
      x.u = *(const uint4*)&Bs[R * 32 + s * 8];
      bfr[ni] = x.v;
    }
#pragma unroll
    for (int mi = 0; mi < 4; mi++)
#pragma unroll
      for (int ni = 0; ni < 4; ni++)
        acc[mi][ni] = __builtin_amdgcn_mfma_f32_16x16x32_bf16(
            af[mi], bfr[ni], acc[mi][ni], 0, 0, 0);
    __syncthreads();   // protect LDS before next stage
  }

  // epilogue — C/D layout: col = lane&15, row = quad*4 + reg  [m89-verified]
  if constexpr (EPI == 0) {
    unsigned short* C = (unsigned short*)Cp + (size_t)bz * sC;
#pragma unroll
    for (int mi = 0; mi < 4; mi++)
#pragma unroll
      for (int r = 0; r < 4; r++) {
        int grow = m0 + wm + mi * 16 + quad * 4 + r;
#pragma unroll
        for (int ni = 0; ni < 4; ni++) {
          int gcol = n0 + wn + ni * 16 + l16;
          C[(size_t)grow * ldc + gcol] = f2bf(acc[mi][ni][r]);
        }
      }
  } else if constexpr (EPI == 1) {
    unsigned short* C = (unsigned short*)Cp + (size_t)bz * sC;
#pragma unroll
    for (int mi = 0; mi < 4; mi++)
#pragma unroll
      for (int r = 0; r < 4; r++) {
        int grow = m0 + wm + mi * 16 + quad * 4 + r;
        float es = 0.f, ts = 0.f;
#pragma unroll
        for (int ni = 0; ni < 4; ni++) {
          int gcol = n0 + wn + ni * 16 + l16;
          float s = acc[mi][ni][r] * scale;
          float e = __expf(s);
          es += e; ts += s * e;
          C[(size_t)grow * ldc + gcol] = f2bf(e);
        }
#pragma unroll
        for (int off = 1; off < 16; off <<= 1) {
          es += __shfl_xor(es, off, 64);
          ts += __shfl_xor(ts, off, 64);
        }
        if (l16 == 0) {
          atomicAdd(&lsum[bz * lstride + grow], es);
          atomicAdd(&tsum[bz * lstride + grow], ts);
        }
      }
  } else {
    float* C = (float*)Cp + (size_t)bz * sC;
#pragma unroll
    for (int mi = 0; mi < 4; mi++)
#pragma unroll
      for (int r = 0; r < 4; r++) {
        int grow = m0 + wm + mi * 16 + quad * 4 + r;
        float linv = 1.0f / lsum[bz * lstride + grow];
#pragma unroll
        for (int ni = 0; ni < 4; ni++) {
          int gcol = n0 + wn + ni * 16 + l16;
          C[(size_t)grow * ldc + gcol] = acc[mi][ni][r] * linv + bias[gcol];
        }
      }
  }
}

// fp32 -> bf16, 8 elems/thread
__global__ __launch_bounds__(256)
void cvt_k(const float* __restrict__ src, unsigned short* __restrict__ dst, int n8)
{
  int stride = gridDim.x * 256;
  for (int i = blockIdx.x * 256 + threadIdx.x; i < n8; i += stride) {
    const float4* s = (const float4*)(src + (size_t)i * 8);
    float4 a = s[0], b = s[1];
    union { unsigned short v[8]; uint4 u; } o;
    o.v[0] = f2bf(a.x); o.v[1] = f2bf(a.y); o.v[2] = f2bf(a.z); o.v[3] = f2bf(a.w);
    o.v[4] = f2bf(b.x); o.v[5] = f2bf(b.y); o.v[6] = f2bf(b.z); o.v[7] = f2bf(b.w);
    *(uint4*)(dst + (size_t)i * 8) = o.u;
  }
}

// W [1024x1024] fp32 -> WT bf16 (WT[e][d] = W[d][e])
__global__ __launch_bounds__(256)
void wtr_k(const float* __restrict__ W, unsigned short* __restrict__ WT)
{
  __shared__ float t[32][33];
  int bx = blockIdx.x * 32, by = blockIdx.y * 32;
  int tx = threadIdx.x & 31, ty = threadIdx.x >> 5;   // ty 0..7
#pragma unroll
  for (int i = 0; i < 32; i += 8)
    t[ty + i][tx] = W[(size_t)(by + ty + i) * D_MODEL + bx + tx];
  __syncthreads();
#pragma unroll
  for (int i = 0; i < 32; i += 8)
    WT[(size_t)(bx + ty + i) * D_MODEL + by + tx] = f2bf(t[tx][ty + i]);
}

// In-place layernorm over rows of 1024 floats.
__global__ __launch_bounds__(256)
void ln_k(float* __restrict__ out, const float* __restrict__ gamma,
          const float* __restrict__ beta)
{
  const size_t row = blockIdx.x;
  float* p = out + row * D_MODEL;
  const int tid = threadIdx.x;
  float v[4]; float s = 0.f, sq = 0.f;
#pragma unroll
  for (int i = 0; i < 4; i++) {
    v[i] = p[tid + i * 256]; s += v[i]; sq += v[i] * v[i];
  }
#pragma unroll
  for (int off = 1; off < 64; off <<= 1) {
    s += __shfl_xor(s, off, 64);
    sq += __shfl_xor(sq, off, 64);
  }
  __shared__ float sh[8];
  int wv = tid >> 6, lane = tid & 63;
  if (lane == 0) { sh[wv] = s; sh[4 + wv] = sq; }
  __syncthreads();
  s  = sh[0] + sh[1] + sh[2] + sh[3];
  sq = sh[4] + sh[5] + sh[6] + sh[7];
  float mean = s * (1.f / 1024.f);
  float var  = sq * (1.f / 1024.f) - mean * mean;
  float rstd = rsqrtf(var + 1e-5f);
#pragma unroll
  for (int i = 0; i < 4; i++) {
    int c = tid + i * 256;
    p[c] = (v[i] - mean) * rstd * gamma[c] + beta[c];
  }
}

// syntony = clip(1 - mean(log l - t/l)/log(S), 0, 1)
__global__ __launch_bounds__(256)
void syn_k(const float* __restrict__ l, const float* __restrict__ t,
           float* __restrict__ out)
{
  float s = 0.f;
  for (int r = threadIdx.x; r < ROWS; r += 256) {
    float lv = l[r];
    s += logf(lv) - t[r] / lv;
  }
#pragma unroll
  for (int off = 1; off < 64; off <<= 1) s += __shfl_xor(s, off, 64);
  __shared__ float sh[4];
  if ((threadIdx.x & 63) == 0) sh[threadIdx.x >> 6] = s;
  __syncthreads();
  if (threadIdx.x == 0) {
    float tot  = sh[0] + sh[1] + sh[2] + sh[3];
    float ment = tot / (float)ROWS;
    float syn  = 1.0f - ment / logf((float)SEQ);
    syn = fminf(fmaxf(syn, 0.f), 1.f);
    out[(size_t)ROWS * D_MODEL] = syn;
  }
}

extern "C" void kernel_launch(void* const* d_in, const int* in_sizes, int n_in,
                              void* d_out, int out_size, void* d_ws, size_t ws_size,
                              hipStream_t stream)
{
  const float* q     = (const float*)d_in[0];
  const float* k     = (const float*)d_in[1];
  const float* v     = (const float*)d_in[2];
  const float* hw    = (const float*)d_in[3];
  const float* hb    = (const float*)d_in[4];
  const float* gamma = (const float*)d_in[5];
  const float* beta  = (const float*)d_in[6];
  float* out = (float*)d_out;

  // ---- workspace: EXACTLY the round-1-proven 96.13 MB footprint ----
  const size_t MB = 1024ull * 1024ull;
  char* ws = (char*)d_ws;
  unsigned short* P   = (unsigned short*)(ws);            // [ 0,64) MB  P bf16
  unsigned short* VWT = (unsigned short*)(ws + 64 * MB);  // [64,96) MB  VWT bf16
  float* lsum = (float*)(ws + 96 * MB);                   // 64 KB
  float* tsum = lsum + ROWS;                              // 64 KB

  // ---- d_out doubles as staging scratch until K2 overwrites it ----
  // phase A (K0): Vb = out[0,32)MB, WT = out[32,34)MB
  // phase B (K1): Qb = out[0,32)MB, Kb = out[32,64)MB
  unsigned short* Vb = (unsigned short*)out;
  unsigned short* WT = (unsigned short*)((char*)out + 32 * MB);
  unsigned short* Qb = (unsigned short*)out;
  unsigned short* Kb = (unsigned short*)((char*)out + 32 * MB);

  hipMemsetAsync(lsum, 0, 2 * ROWS * sizeof(float), stream);

  const int n8 = ROWS * D_MODEL / 8;   // 2M vec8 per tensor

  // phase A: VWT = WT . Vb^T
  cvt_k<<<4096, 256, 0, stream>>>(v, Vb, n8);
  wtr_k<<<dim3(32, 32), 256, 0, stream>>>(hw, WT);
  gemm_a<0><<<dim3(ROWS / 128, D_MODEL / 128, 1), 256, 0, stream>>>(
      WT, Vb, VWT, D_MODEL, D_MODEL, ROWS, D_MODEL,
      0, 0, 0, 1.f, nullptr, nullptr, 0, nullptr);

  // phase B: P = exp(Qb Kb^T / 32) + row sums l,t   (Vb/WT dead -> reuse)
  cvt_k<<<4096, 256, 0, stream>>>(q, Qb, n8);
  cvt_k<<<4096, 256, 0, stream>>>(k, Kb, n8);
  gemm_a<1><<<dim3(SEQ / 128, SEQ / 128, BATCH), 256, 0, stream>>>(
      Qb, Kb, P, D_MODEL, D_MODEL, SEQ, D_MODEL,
      (size_t)SEQ * D_MODEL, (size_t)SEQ * D_MODEL, (size_t)SEQ * SEQ,
      0.03125f, lsum, tsum, SEQ, nullptr);

  // phase C: out = (P . VWT^T)/l + bias   (Qb/Kb dead; out overwritten)
  // per-batch B offset is a COLUMN offset into VWT: sB = 2048 elements.
  gemm_a<2><<<dim3(D_MODEL / 128, SEQ / 128, BATCH), 256, 0, stream>>>(
      P, VWT, out, SEQ, ROWS, D_MODEL, SEQ,
      (size_t)SEQ * SEQ, (size_t)SEQ, (size_t)SEQ * D_MODEL,
      1.f, lsum, tsum, SEQ, hb);

  ln_k<<<ROWS, 256, 0, stream>>>(out, gamma, beta);
  syn_k<<<1, 256, 0, stream>>>(lsum, tsum, out);
}